// Round 1
// baseline (541.849 us; speedup 1.0000x reference)
//
#include <hip/hip_runtime.h>
#include <math.h>

#define T_TOK  16384
#define HID    4096
#define NEXP   64
#define KSPLIT 4
#define KRANGE (HID / KSPLIT)   // 1024
#define NCHUNK (KRANGE / 32)    // 32 K-chunks of 32

typedef __attribute__((ext_vector_type(8))) short short8;
typedef __attribute__((ext_vector_type(4))) float float4v;

// d_ws: partial [KSPLIT][T_TOK][NEXP] f32 (16.8MB), then wh/wm/wl u16 (3x512KB)
#define PART_ELEMS ((size_t)KSPLIT * T_TOK * NEXP)
#define WHALF      ((size_t)NEXP * HID)

__device__ __forceinline__ unsigned short rne_bf16(float f) {
  unsigned u = __float_as_uint(f);
  unsigned r = u + 0x7FFFu + ((u >> 16) & 1u);
  return (unsigned short)(r >> 16);
}
__device__ __forceinline__ float bf16_f(unsigned short h) {
  return __uint_as_float(((unsigned)h) << 16);
}

// 3-way bf16 split of w: f = hi+mid+lo + O(2^-26 |f|). Subtractions exact
// (Sterbenz), RNE rounding at each stage.
__global__ void w_convert3(const float* __restrict__ w,
                           unsigned short* __restrict__ wh,
                           unsigned short* __restrict__ wm,
                           unsigned short* __restrict__ wl) {
  int t = blockIdx.x * 256 + threadIdx.x;
#pragma unroll
  for (int j = 0; j < 4; ++j) {
    int idx = t + j * 65536;
    float f = w[idx];
    unsigned short h = rne_bf16(f);
    float r1 = f - bf16_f(h);
    unsigned short m = rne_bf16(r1);
    float r2 = r1 - bf16_f(m);
    wh[idx] = h; wm[idx] = m; wl[idx] = rne_bf16(r2);
  }
}

// Wave = 16 tokens x 64 experts x K-range 1024 (4096 waves -> 4 waves/SIMD).
// Issue discipline: within each chunk sub-block all B loads (L2) are issued
// BEFORE the HBM A prefetch, so vmcnt FIFO waits on B never drain an
// outstanding A load. A prefetch distance = 3 chunks (4 rotating buffers).
// 6 MFMA product terms per tile for f32-grade logits (numerics identical to
// previous version; per-token accumulation order unchanged).
__global__ __launch_bounds__(256, 4)
void router_gemm(const float* __restrict__ x,
                 const unsigned short* __restrict__ wh,
                 const unsigned short* __restrict__ wm,
                 const unsigned short* __restrict__ wl,
                 float* __restrict__ partial) {
  const int lane = threadIdx.x & 63;
  const int wid  = threadIdx.x >> 6;
  const int W    = blockIdx.x * 4 + wid;       // 0..4095
  const int ks   = W & (KSPLIT - 1);
  const int t0   = (W >> 2) * 16;
  const int r    = lane & 15;
  const int q    = lane >> 4;
  const int k0   = ks * KRANGE + q * 8;

  const float* pa0 = x + (size_t)(t0 + r) * HID + k0;
  const unsigned short* pb[3];
  pb[0] = wh + (size_t)r * HID + k0;
  pb[1] = wm + (size_t)r * HID + k0;
  pb[2] = wl + (size_t)r * HID + k0;

  float4v acc[4];
#pragma unroll
  for (int n = 0; n < 4; ++n) acc[n] = (float4v)(0.f);

  float4 araw[4][2];        // [buf][half-of-8]
  short8 ah, am_, al;
  short8 Bb[2][2][3];       // [half][n_local][split]

#define LOADA(buf, c) do {                                                   \
    const int _o = (c) * 32;                                                 \
    araw[buf][0] = *(const float4*)(pa0 + _o);                               \
    araw[buf][1] = *(const float4*)(pa0 + _o + 4);                           \
  } while (0)

#define LOADB(half, c) do {                                                  \
    const int _o = (c) * 32;                                                 \
    _Pragma("unroll")                                                        \
    for (int _nl = 0; _nl < 2; ++_nl) {                                      \
      const size_t _nb = (size_t)((half) * 2 + _nl) * 16 * HID + _o;         \
      _Pragma("unroll")                                                      \
      for (int _s = 0; _s < 3; ++_s)                                         \
        Bb[half][_nl][_s] = *(const short8*)(pb[_s] + _nb);                  \
    }                                                                        \
  } while (0)

#define SPLITA(buf) do {                                                     \
    const float4 _v0 = araw[buf][0], _v1 = araw[buf][1];                     \
    float _f[8] = {_v0.x,_v0.y,_v0.z,_v0.w,_v1.x,_v1.y,_v1.z,_v1.w};         \
    _Pragma("unroll")                                                        \
    for (int _j = 0; _j < 8; ++_j) {                                         \
      unsigned short _h = rne_bf16(_f[_j]);                                  \
      float _r1 = _f[_j] - bf16_f(_h);                                       \
      unsigned short _mm = rne_bf16(_r1);                                    \
      float _r2 = _r1 - bf16_f(_mm);                                         \
      ah[_j] = (short)_h; am_[_j] = (short)_mm;                              \
      al[_j] = (short)rne_bf16(_r2);                                         \
    }                                                                        \
  } while (0)

#define MFMAH(half) do {                                                     \
    _Pragma("unroll")                                                        \
    for (int _nl = 0; _nl < 2; ++_nl) {                                      \
      const int _n = (half) * 2 + _nl;                                       \
      const short8 _BH = Bb[half][_nl][0];                                   \
      const short8 _BM = Bb[half][_nl][1];                                   \
      const short8 _BL = Bb[half][_nl][2];                                   \
      float4v _a = acc[_n];                                                  \
      _a = __builtin_amdgcn_mfma_f32_16x16x32_bf16(al,  _BH, _a, 0, 0, 0);   \
      _a = __builtin_amdgcn_mfma_f32_16x16x32_bf16(ah,  _BL, _a, 0, 0, 0);   \
      _a = __builtin_amdgcn_mfma_f32_16x16x32_bf16(am_, _BM, _a, 0, 0, 0);   \
      _a = __builtin_amdgcn_mfma_f32_16x16x32_bf16(am_, _BH, _a, 0, 0, 0);   \
      _a = __builtin_amdgcn_mfma_f32_16x16x32_bf16(ah,  _BM, _a, 0, 0, 0);   \
      _a = __builtin_amdgcn_mfma_f32_16x16x32_bf16(ah,  _BH, _a, 0, 0, 0);   \
      acc[_n] = _a;                                                          \
    }                                                                        \
  } while (0)

  // A prefetch distance 3 (bufs 0..2), B half-pipelined one half-phase ahead.
  LOADA(0, 0); LOADA(1, 1); LOADA(2, 2);
  LOADB(0, 0);
  for (int cc = 0; cc < NCHUNK; cc += 4) {
    // chunk cc+0, buf 0
    LOADB(1, cc);
    SPLITA(0);
    MFMAH(0);
    LOADB(0, cc + 1);
    MFMAH(1);
    if (cc + 3 < NCHUNK) LOADA(3, cc + 3);

    // chunk cc+1, buf 1
    LOADB(1, cc + 1);
    SPLITA(1);
    MFMAH(0);
    LOADB(0, cc + 2);
    MFMAH(1);
    if (cc + 4 < NCHUNK) LOADA(0, cc + 4);

    // chunk cc+2, buf 2
    LOADB(1, cc + 2);
    SPLITA(2);
    MFMAH(0);
    LOADB(0, cc + 3);
    MFMAH(1);
    if (cc + 5 < NCHUNK) LOADA(1, cc + 5);

    // chunk cc+3, buf 3
    LOADB(1, cc + 3);
    SPLITA(3);
    MFMAH(0);
    if (cc + 4 < NCHUNK) LOADB(0, cc + 4);
    MFMAH(1);
    if (cc + 6 < NCHUNK) LOADA(2, cc + 6);
  }
#undef LOADA
#undef LOADB
#undef SPLITA
#undef MFMAH

  // D[row=(lane>>4)*4+reg][col=lane&15]  (m89/m91-verified)
  float* po = partial + ((size_t)ks * T_TOK + t0) * NEXP;
#pragma unroll
  for (int n = 0; n < 4; ++n)
#pragma unroll
    for (int rr = 0; rr < 4; ++rr)
      po[(size_t)(q * 4 + rr) * NEXP + n * 16 + r] = acc[n][rr];
}

// One wave per token, lane = expert. Reduce KSPLIT partials, write logits,
// top-8 on logits (softmax monotone; denominator cancels in renorm),
// ties -> lowest index (lax.top_k semantics).
__global__ __launch_bounds__(256)
void router_topk(const float* __restrict__ partial,
                 float* __restrict__ logits_out,
                 float* __restrict__ scores_out,
                 float* __restrict__ idx_out) {
  const int lane = threadIdx.x & 63;
  const int wid  = threadIdx.x >> 6;
  const int t    = blockIdx.x * 4 + wid;

  float ps[KSPLIT];
#pragma unroll
  for (int s = 0; s < KSPLIT; ++s)
    ps[s] = partial[((size_t)s * T_TOK + t) * NEXP + lane];
  float l = (ps[0] + ps[1]) + (ps[2] + ps[3]);
  logits_out[(size_t)t * NEXP + lane] = l;

  float m = l;
#pragma unroll
  for (int off = 32; off >= 1; off >>= 1)
    m = fmaxf(m, __shfl_xor(m, off, 64));
  float p = __expf(l - m);

  float v = l;
  float myscore = 0.f, myidx = 0.f, ssum = 0.f;
#pragma unroll
  for (int k = 0; k < 8; ++k) {
    float bv = v; int bi = lane;
#pragma unroll
    for (int off = 32; off >= 1; off >>= 1) {
      float ov = __shfl_xor(bv, off, 64);
      int   oi = __shfl_xor(bi, off, 64);
      if (ov > bv || (ov == bv && oi < bi)) { bv = ov; bi = oi; }
    }
    float pw = __shfl(p, bi, 64);
    ssum += pw;
    if (lane == k)  { myscore = pw; myidx = (float)bi; }
    if (lane == bi) v = -INFINITY;
  }
  if (lane < 8) {
    scores_out[(size_t)t * 8 + lane] = myscore / ssum;
    idx_out[(size_t)t * 8 + lane]    = myidx;
  }
}

extern "C" void kernel_launch(void* const* d_in, const int* in_sizes, int n_in,
                              void* d_out, int out_size, void* d_ws, size_t ws_size,
                              hipStream_t stream) {
  const float* x = (const float*)d_in[0];   // [16384, 4096]
  const float* w = (const float*)d_in[1];   // [64, 4096]
  float* out    = (float*)d_out;
  float* logits = out;                                   // [T,64]
  float* scores = out + (size_t)T_TOK * NEXP;            // [T,8]
  float* idxo   = scores + (size_t)T_TOK * 8;            // [T,8]

  float* partial = (float*)d_ws;
  unsigned short* wh = (unsigned short*)((char*)d_ws + PART_ELEMS * sizeof(float));
  unsigned short* wm = wh + WHALF;
  unsigned short* wl = wm + WHALF;

  hipLaunchKernelGGL(w_convert3, dim3(256), dim3(256), 0, stream, w, wh, wm, wl);
  hipLaunchKernelGGL(router_gemm, dim3(4096 / 4), dim3(256), 0, stream,
                     x, wh, wm, wl, partial);
  hipLaunchKernelGGL(router_topk, dim3(T_TOK / 4), dim3(256), 0, stream,
                     partial, logits, scores, idxo);
}

// Round 3
// 395.763 us; speedup vs baseline: 1.3691x; 1.3691x over previous
//
#include <hip/hip_runtime.h>
#include <math.h>

#define T_TOK  16384
#define HID    4096
#define NEXP   64
#define KSPLIT 4
#define KRANGE (HID / KSPLIT)   // 1024, 32 chunks of 32 K

typedef __attribute__((ext_vector_type(8))) short short8;
typedef __attribute__((ext_vector_type(4))) float float4v;

// d_ws: partial [KSPLIT][T_TOK][NEXP] f32 (16.8MB), then wh/wm/wl u16
// (3x512KB, CONTIGUOUS — gemm indexes them as one [3][64][4096] array)
#define PART_ELEMS ((size_t)KSPLIT * T_TOK * NEXP)
#define WHALF      ((size_t)NEXP * HID)

__device__ __forceinline__ unsigned short rne_bf16(float f) {
  unsigned u = __float_as_uint(f);
  unsigned r = u + 0x7FFFu + ((u >> 16) & 1u);
  return (unsigned short)(r >> 16);
}
__device__ __forceinline__ float bf16_f(unsigned short h) {
  return __uint_as_float(((unsigned)h) << 16);
}

// 3-way bf16 split of w: f = hi+mid+lo + O(2^-26 |f|). Subtractions exact
// (Sterbenz), RNE rounding at each stage.
__global__ void w_convert3(const float* __restrict__ w,
                           unsigned short* __restrict__ wh,
                           unsigned short* __restrict__ wm,
                           unsigned short* __restrict__ wl) {
  int t = blockIdx.x * 256 + threadIdx.x;
#pragma unroll
  for (int j = 0; j < 4; ++j) {
    int idx = t + j * 65536;
    float f = w[idx];
    unsigned short h = rne_bf16(f);
    float r1 = f - bf16_f(h);
    unsigned short m = rne_bf16(r1);
    float r2 = r1 - bf16_f(m);
    wh[idx] = h; wm[idx] = m; wl[idx] = rne_bf16(r2);
  }
}

// Wave = 32 tokens (2 m-tiles) x 64 experts x K-range 1024. Block = 4 waves,
// 128 tokens, all same ks => B group-tiles (64 K x 64 e x 3 splits = 24KB)
// shared via LDS, double-buffered (48KB). B staged with global_load_lds
// (pre-swizzled global source, linear LDS dest; XOR swizzle ((e&7)<<4) makes
// ds_read_b128 conflict-free). MFMA B-deps are lgkmcnt-only; A-deps are
// counted vmcnt on loads 4 chunks old. Raw s_barrier + manual
// s_waitcnt vmcnt(8) keeps A prefetches in flight across swaps (never
// drains to 0 in the main loop).
__global__ __launch_bounds__(256, 2)
void router_gemm(const float* __restrict__ x,
                 const unsigned short* __restrict__ wh,
                 float* __restrict__ partial) {
  __shared__ float4 ldsb4[3072];            // 48 KiB, 16B aligned
  char* ldsc = (char*)ldsb4;
  const int tid  = threadIdx.x;
  const int lane = tid & 63;
  const int wid  = tid >> 6;
  const int b    = blockIdx.x;
  const int ks   = b & (KSPLIT - 1);
  const int t0   = (b >> 2) * 128 + wid * 32;
  const int r    = lane & 15;
  const int q    = lane >> 4;

  const float* pa0 = x + (size_t)(t0 + r) * HID + ks * KRANGE + q * 8;
  const float* pa1 = pa0 + (size_t)16 * HID;

  // Staging source pointers: linear LDS byte o -> (s,e,kb_swz); fetch the
  // global element that belongs at o under the swizzled image (m173 pattern).
  const char* sp[6];
#pragma unroll
  for (int it = 0; it < 6; ++it) {
    int o  = it * 4096 + tid * 16;          // linear byte in 24KB image
    int s  = o >> 13;                       // split 0..2
    int e  = (o >> 7) & 63;                 // expert row
    int kb = (o & 127) ^ ((e & 7) << 4);    // unswizzled k-byte in group
    sp[it] = (const char*)wh + (size_t)s * 524288 + (size_t)e * 8192
           + ks * 2048 + kb;
  }

  // Per-lane swizzled ds_read addresses (chunk-in-group cl = 0 / 1).
  const int swz = (r & 7) << 4;
  const int a0 = r * 128 + ((q * 16) ^ swz);
  const int a1 = r * 128 + ((q * 16 + 64) ^ swz);

  float4v acc[2][4];
#pragma unroll
  for (int m = 0; m < 2; ++m)
#pragma unroll
    for (int n = 0; n < 4; ++n) acc[m][n] = (float4v)(0.f);

  float4 araw[4][2][2];                     // [chunk%4][m][half-of-8]
  short8 ah[2], am_[2], al[2];

#define STAGE(buf) do {                                                      \
    _Pragma("unroll")                                                        \
    for (int _it = 0; _it < 6; ++_it) {                                      \
      __builtin_amdgcn_global_load_lds(                                      \
        (const __attribute__((address_space(1))) unsigned int*)sp[_it],      \
        (__attribute__((address_space(3))) unsigned int*)                    \
          (ldsc + (buf) * 24576 + _it * 4096 + wid * 1024),                  \
        16, 0, 0);                                                           \
      sp[_it] += 128;                                                        \
    }                                                                        \
  } while (0)

#define LOADA(slot, c) do {                                                  \
    const int _o = (c) * 32;                                                 \
    araw[slot][0][0] = *(const float4*)(pa0 + _o);                           \
    araw[slot][0][1] = *(const float4*)(pa0 + _o + 4);                       \
    araw[slot][1][0] = *(const float4*)(pa1 + _o);                           \
    araw[slot][1][1] = *(const float4*)(pa1 + _o + 4);                       \
  } while (0)

#define SPLITA(slot) do {                                                    \
    _Pragma("unroll")                                                        \
    for (int _m = 0; _m < 2; ++_m) {                                         \
      const float4 _v0 = araw[slot][_m][0], _v1 = araw[slot][_m][1];         \
      float _f[8] = {_v0.x,_v0.y,_v0.z,_v0.w,_v1.x,_v1.y,_v1.z,_v1.w};       \
      _Pragma("unroll")                                                      \
      for (int _j = 0; _j < 8; ++_j) {                                       \
        unsigned short _h = rne_bf16(_f[_j]);                                \
        float _r1 = _f[_j] - bf16_f(_h);                                     \
        unsigned short _mm = rne_bf16(_r1);                                  \
        float _r2 = _r1 - bf16_f(_mm);                                       \
        ah[_m][_j] = (short)_h; am_[_m][_j] = (short)_mm;                    \
        al[_m][_j] = (short)rne_bf16(_r2);                                   \
      }                                                                      \
    }                                                                        \
  } while (0)

#define CHUNK(buf, cl) do {                                                  \
    _Pragma("unroll")                                                        \
    for (int _h = 0; _h < 2; ++_h) {                                         \
      short8 _B[2][3];                                                       \
      _Pragma("unroll")                                                      \
      for (int _nl = 0; _nl < 2; ++_nl)                                      \
        _Pragma("unroll")                                                    \
        for (int _s = 0; _s < 3; ++_s)                                       \
          _B[_nl][_s] = *(const short8*)(ldsc + (buf) * 24576 + _s * 8192    \
              + (_h * 2 + _nl) * 2048 + ((cl) ? a1 : a0));                   \
      _Pragma("unroll")                                                      \
      for (int _nl = 0; _nl < 2; ++_nl) {                                    \
        const int _n = _h * 2 + _nl;                                         \
        const short8 _BH = _B[_nl][0], _BM = _B[_nl][1], _BL = _B[_nl][2];   \
        _Pragma("unroll")                                                    \
        for (int _m = 0; _m < 2; ++_m) {                                     \
          float4v _a = acc[_m][_n];                                          \
          _a = __builtin_amdgcn_mfma_f32_16x16x32_bf16(al[_m],  _BH, _a,0,0,0);\
          _a = __builtin_amdgcn_mfma_f32_16x16x32_bf16(ah[_m],  _BL, _a,0,0,0);\
          _a = __builtin_amdgcn_mfma_f32_16x16x32_bf16(am_[_m], _BM, _a,0,0,0);\
          _a = __builtin_amdgcn_mfma_f32_16x16x32_bf16(am_[_m], _BH, _a,0,0,0);\
          _a = __builtin_amdgcn_mfma_f32_16x16x32_bf16(ah[_m],  _BM, _a,0,0,0);\
          _a = __builtin_amdgcn_mfma_f32_16x16x32_bf16(ah[_m],  _BH, _a,0,0,0);\
          acc[_m][_n] = _a;                                                  \
        }                                                                    \
      }                                                                      \
    }                                                                        \
  } while (0)

  // Prologue: group0 -> buf0; A chunks 0..3.
  STAGE(0);
  LOADA(0, 0); LOADA(1, 1); LOADA(2, 2); LOADA(3, 3);
  asm volatile("s_waitcnt vmcnt(16)" ::: "memory");   // stage done, A in flight
  __builtin_amdgcn_s_barrier();

  for (int gg = 0; gg < 7; ++gg) {
    const int c0 = gg * 4;
    // body0: read buf0 (chunks c0,c0+1), stage buf1 (next group)
    STAGE(1);
    SPLITA(0); CHUNK(0, 0);
    LOADA(0, c0 + 4);
    SPLITA(1); CHUNK(0, 1);
    LOADA(1, c0 + 5);
    asm volatile("s_waitcnt vmcnt(8)" ::: "memory");  // stage retired, 8 A live
    __builtin_amdgcn_s_barrier();
    // body1: read buf1 (chunks c0+2,c0+3), stage buf0 (next group)
    STAGE(0);
    SPLITA(2); CHUNK(1, 0);
    LOADA(2, c0 + 6);
    SPLITA(3); CHUNK(1, 1);
    LOADA(3, c0 + 7);
    asm volatile("s_waitcnt vmcnt(8)" ::: "memory");
    __builtin_amdgcn_s_barrier();
  }
  // Epilogue: chunks 28..31 (A already in araw0..3; group14 in buf0).
  STAGE(1);                                           // group15
  SPLITA(0); CHUNK(0, 0);
  SPLITA(1); CHUNK(0, 1);
  asm volatile("s_waitcnt vmcnt(0)" ::: "memory");
  __builtin_amdgcn_s_barrier();
  SPLITA(2); CHUNK(1, 0);
  SPLITA(3); CHUNK(1, 1);
#undef STAGE
#undef LOADA
#undef SPLITA
#undef CHUNK

  // D[row=(lane>>4)*4+reg][col=lane&15]  (m89/m91-verified)
  float* po = partial + ((size_t)ks * T_TOK + t0) * NEXP;
#pragma unroll
  for (int m = 0; m < 2; ++m)
#pragma unroll
    for (int n = 0; n < 4; ++n)
#pragma unroll
      for (int rr = 0; rr < 4; ++rr)
        po[(size_t)(m * 16 + q * 4 + rr) * NEXP + n * 16 + r] = acc[m][n][rr];
}

// One wave per 64 tokens. Coalesced load+reduce (lane=expert), LDS transpose
// (stride 68 floats: 16B-aligned rows, conflict-free), then per-lane
// in-register top-8 insertion (strict > with ascending index = lax.top_k tie
// semantics). No cross-lane ops in selection.
__global__ __launch_bounds__(64)
void router_topk(const float* __restrict__ partial,
                 float* __restrict__ logits_out,
                 float* __restrict__ scores_out,
                 float* __restrict__ idx_out) {
  __shared__ float lt[64 * 68];
  const int lane = threadIdx.x;
  const int t0   = blockIdx.x * 64;

#pragma unroll
  for (int tt = 0; tt < 64; ++tt) {
    const size_t tb = (size_t)(t0 + tt) * NEXP + lane;
    float a0 = partial[tb];
    float a1 = partial[(size_t)1 * T_TOK * NEXP + tb];
    float a2 = partial[(size_t)2 * T_TOK * NEXP + tb];
    float a3 = partial[(size_t)3 * T_TOK * NEXP + tb];
    float l  = (a0 + a1) + (a2 + a3);
    logits_out[(size_t)(t0 + tt) * NEXP + lane] = l;
    lt[tt * 68 + lane] = l;
  }
  __syncthreads();

  float rowf[64];
#pragma unroll
  for (int i = 0; i < 16; ++i) {
    float4 v = *(const float4*)&lt[lane * 68 + i * 4];
    rowf[i * 4 + 0] = v.x; rowf[i * 4 + 1] = v.y;
    rowf[i * 4 + 2] = v.z; rowf[i * 4 + 3] = v.w;
  }

  float tv[8]; int ti[8];
#pragma unroll
  for (int k2 = 0; k2 < 8; ++k2) { tv[k2] = -INFINITY; ti[k2] = 0; }
#pragma unroll
  for (int j = 0; j < 64; ++j) {
    float v = rowf[j]; int id = j;
#pragma unroll
    for (int k2 = 0; k2 < 8; ++k2) {
      bool g2 = v > tv[k2];
      float nv = g2 ? v : tv[k2];
      int   ni = g2 ? id : ti[k2];
      float ov = g2 ? tv[k2] : v;
      int   oi = g2 ? ti[k2] : id;
      tv[k2] = nv; ti[k2] = ni; v = ov; id = oi;
    }
  }

  const float mx = tv[0];
  float p[8]; float ssum = 0.f;
#pragma unroll
  for (int k2 = 0; k2 < 8; ++k2) { p[k2] = __expf(tv[k2] - mx); ssum += p[k2]; }
  const float inv = 1.0f / ssum;
  const size_t t = (size_t)(t0 + lane);
#pragma unroll
  for (int k2 = 0; k2 < 8; ++k2) {
    scores_out[t * 8 + k2] = p[k2] * inv;
    idx_out[t * 8 + k2]    = (float)ti[k2];
  }
}

extern "C" void kernel_launch(void* const* d_in, const int* in_sizes, int n_in,
                              void* d_out, int out_size, void* d_ws, size_t ws_size,
                              hipStream_t stream) {
  const float* x = (const float*)d_in[0];   // [16384, 4096]
  const float* w = (const float*)d_in[1];   // [64, 4096]
  float* out    = (float*)d_out;
  float* logits = out;                                   // [T,64]
  float* scores = out + (size_t)T_TOK * NEXP;            // [T,8]
  float* idxo   = scores + (size_t)T_TOK * 8;            // [T,8]

  float* partial = (float*)d_ws;
  unsigned short* wh = (unsigned short*)((char*)d_ws + PART_ELEMS * sizeof(float));
  unsigned short* wm = wh + WHALF;
  unsigned short* wl = wm + WHALF;

  hipLaunchKernelGGL(w_convert3, dim3(256), dim3(256), 0, stream, w, wh, wm, wl);
  hipLaunchKernelGGL(router_gemm, dim3(512), dim3(256), 0, stream,
                     x, wh, partial);
  hipLaunchKernelGGL(router_topk, dim3(T_TOK / 64), dim3(64), 0, stream,
                     partial, logits, scores, idxo);
}